// Round 1
// baseline (479.067 us; speedup 1.0000x reference)
//
#include <hip/hip_runtime.h>

// Tiny ConvGRUCell, fully fused. B=8, C=32, H=W=256.
// x,h: [B,32,256,256] f32.  Weights [32,32] row-major (w[o][c]), biases [32].
// Outputs concatenated: y [B,32,256,256], h_t [B,32,256,256], both f32.

constexpr int C     = 32;
constexpr int HWSZ  = 256 * 256;          // pixels per (b, channel) plane
constexpr int NPIX  = 8 * HWSZ;           // total pixels = 524288

__device__ __forceinline__ float sigm(float v) {
    v = fminf(fmaxf(v, -30.f), 30.f);
    float e = __expf(-v);                       // v_exp_f32
    return __builtin_amdgcn_rcpf(1.f + e);      // 1-ulp rcp
}

__device__ __forceinline__ float tanh_fast(float v) {
    v = fminf(fmaxf(v, -15.f), 15.f);
    float e = __expf(-2.f * v);
    // (1-e)/(1+e)
    return 1.f - 2.f * e * __builtin_amdgcn_rcpf(1.f + e);
}

__global__ __launch_bounds__(256) void gru_fused(
    const float* __restrict__ x,   const float* __restrict__ h,
    const float* __restrict__ w_xz, const float* __restrict__ b_xz,
    const float* __restrict__ w_hz, const float* __restrict__ b_hz,
    const float* __restrict__ w_xr, const float* __restrict__ b_xr,
    const float* __restrict__ w_hr, const float* __restrict__ b_hr,
    const float* __restrict__ w_c,  const float* __restrict__ b_c,
    const float* __restrict__ w_u,  const float* __restrict__ b_u,
    const float* __restrict__ w_o,  const float* __restrict__ b_o,
    float* __restrict__ y, float* __restrict__ h_t)
{
    const int p  = blockIdx.x * blockDim.x + threadIdx.x;  // pixel id
    const int b  = p >> 16;                                // / 65536
    const int hw = p & 65535;
    const int base = b * (C * HWSZ) + hw;                  // < 2^25, int ok

    // ---- load per-pixel channel vectors (coalesced across lanes) ----
    float xv[C], hv[C];
#pragma unroll
    for (int c = 0; c < C; ++c) {
        xv[c] = x[base + c * HWSZ];
        hv[c] = h[base + c * HWSZ];
    }

    // ---- z gate ----
    float zv[C];
#pragma unroll 1
    for (int o = 0; o < C; ++o) {
        float a = b_xz[o] + b_hz[o];
#pragma unroll
        for (int c = 0; c < C; ++c) {
            a = fmaf(w_xz[o * C + c], xv[c], a);
            a = fmaf(w_hz[o * C + c], hv[c], a);
        }
        zv[o] = sigm(a);
    }

    // ---- r gate, then rh = r * h ----
    float rh[C];
#pragma unroll 1
    for (int o = 0; o < C; ++o) {
        float a = b_xr[o] + b_hr[o];
#pragma unroll
        for (int c = 0; c < C; ++c) {
            a = fmaf(w_xr[o * C + c], xv[c], a);
            a = fmaf(w_hr[o * C + c], hv[c], a);
        }
        rh[o] = sigm(a) * hv[o];
    }

    // ---- candidate + state update ----
    float htv[C];
#pragma unroll 1
    for (int o = 0; o < C; ++o) {
        float a = b_c[o] + b_u[o];
#pragma unroll
        for (int c = 0; c < C; ++c) {
            a = fmaf(w_c[o * C + c], xv[c], a);
            a = fmaf(w_u[o * C + c], rh[c], a);
        }
        float hh = tanh_fast(a);
        // (1-z)*h + z*hh == h + z*(hh-h)
        htv[o] = fmaf(zv[o], hh - hv[o], hv[o]);
    }

    // ---- store h_t (second output) ----
#pragma unroll
    for (int o = 0; o < C; ++o)
        h_t[base + o * HWSZ] = htv[o];

    // ---- output projection y ----
#pragma unroll 1
    for (int o = 0; o < C; ++o) {
        float a = b_o[o];
#pragma unroll
        for (int c = 0; c < C; ++c)
            a = fmaf(w_o[o * C + c], htv[c], a);
        y[base + o * HWSZ] = a;
    }
}

extern "C" void kernel_launch(void* const* d_in, const int* in_sizes, int n_in,
                              void* d_out, int out_size, void* d_ws, size_t ws_size,
                              hipStream_t stream) {
    const float* x    = (const float*)d_in[0];
    const float* h    = (const float*)d_in[1];
    const float* w_xz = (const float*)d_in[2];
    const float* b_xz = (const float*)d_in[3];
    const float* w_hz = (const float*)d_in[4];
    const float* b_hz = (const float*)d_in[5];
    const float* w_xr = (const float*)d_in[6];
    const float* b_xr = (const float*)d_in[7];
    const float* w_hr = (const float*)d_in[8];
    const float* b_hr = (const float*)d_in[9];
    const float* w_c  = (const float*)d_in[10];
    const float* b_c  = (const float*)d_in[11];
    const float* w_u  = (const float*)d_in[12];
    const float* b_u  = (const float*)d_in[13];
    const float* w_o  = (const float*)d_in[14];
    const float* b_o  = (const float*)d_in[15];

    float* y   = (float*)d_out;                 // [8,32,256,256]
    float* h_t = (float*)d_out + (size_t)NPIX * 1;  // note: NPIX*1? see below

    // y has B*COUT*H*W = 8*32*65536 = 16,777,216 elements; h_t follows.
    h_t = (float*)d_out + (size_t)8 * 32 * HWSZ;

    dim3 block(256);
    dim3 grid(NPIX / 256);   // 2048 blocks, exact

    gru_fused<<<grid, block, 0, stream>>>(x, h,
        w_xz, b_xz, w_hz, b_hz, w_xr, b_xr, w_hr, b_hr,
        w_c, b_c, w_u, b_u, w_o, b_o, y, h_t);
}

// Round 2
// 284.958 us; speedup vs baseline: 1.6812x; 1.6812x over previous
//
#include <hip/hip_runtime.h>

// Fused ConvGRUCell via bf16 MFMA. B=8, C=32, H=W=256.
// GEMM view: for each gate, D[o][p] = sum_c W[o][c] * V[c][p] over all pixels p.
// One wave owns a 32-pixel tile and computes all 7 matvecs with
// v_mfma_f32_32x32x16_bf16 (A = weights, B = activations, f32 accumulate).

typedef __attribute__((ext_vector_type(8)))  __bf16   bf16x8;
typedef __attribute__((ext_vector_type(16))) float    f32x16;
typedef __attribute__((ext_vector_type(4)))  unsigned uint4v;

constexpr int C     = 32;
constexpr int HWSZ  = 256 * 256;       // 65536
constexpr int BSTR  = C * HWSZ;        // batch stride 2,097,152
constexpr int NPIX  = 8 * HWSZ;        // 524288
constexpr int NTILE = NPIX / 32;       // 16384

#define MFMA(a, b, c) __builtin_amdgcn_mfma_f32_32x32x16_bf16((a), (b), (c), 0, 0, 0)

__device__ __forceinline__ unsigned pk2(float a, float b) {
    unsigned short ua = __builtin_bit_cast(unsigned short, (__bf16)a);
    unsigned short ub = __builtin_bit_cast(unsigned short, (__bf16)b);
    return (unsigned)ua | ((unsigned)ub << 16);
}
__device__ __forceinline__ bf16x8 mkfrag(unsigned a, unsigned b, unsigned c, unsigned d) {
    uint4v u = {a, b, c, d};
    return __builtin_bit_cast(bf16x8, u);
}

__device__ __forceinline__ float sigm(float v) {
    v = fminf(fmaxf(v, -30.f), 30.f);
    float e = __expf(-v);
    return __builtin_amdgcn_rcpf(1.f + e);
}
__device__ __forceinline__ float tanh_fast(float v) {
    v = fminf(fmaxf(v, -15.f), 15.f);
    float e = __expf(-2.f * v);
    return 1.f - 2.f * e * __builtin_amdgcn_rcpf(1.f + e);
}

// acc layout (32x32 C/D): lane holds col = lane&31 (pixel), rows
// (i&3) + 8*(i>>2) + 4*(lane>>5) for reg i in [0,16).
// B-frag layout: lane holds col = lane&31 (pixel), k = (lane>>5)*8 + j (+16 for frag1).
// Lane l and l^32 hold the SAME pixel column -> permlane32_swap exchanges the
// complementary row groups (newD.hi <- S.lo, newS.lo <- D.hi).
__device__ __forceinline__ void acc2frag(const f32x16 v, bf16x8& f0, bf16x8& f1) {
    unsigned A  = pk2(v[0],  v[1]),  B  = pk2(v[2],  v[3]);
    unsigned Cc = pk2(v[4],  v[5]),  D  = pk2(v[6],  v[7]);
    auto s0 = __builtin_amdgcn_permlane32_swap(A, Cc, false, false);
    auto s1 = __builtin_amdgcn_permlane32_swap(B, D,  false, false);
    f0 = mkfrag(s0[0], s1[0], s0[1], s1[1]);
    unsigned A2 = pk2(v[8],  v[9]),  B2 = pk2(v[10], v[11]);
    unsigned C2 = pk2(v[12], v[13]), D2 = pk2(v[14], v[15]);
    auto s2 = __builtin_amdgcn_permlane32_swap(A2, C2, false, false);
    auto s3 = __builtin_amdgcn_permlane32_swap(B2, D2, false, false);
    f1 = mkfrag(s2[0], s3[0], s2[1], s3[1]);
}

__global__ __launch_bounds__(256, 2) void gru_mfma(
    const float* __restrict__ x,    const float* __restrict__ h,
    const float* __restrict__ w_xz, const float* __restrict__ b_xz,
    const float* __restrict__ w_hz, const float* __restrict__ b_hz,
    const float* __restrict__ w_xr, const float* __restrict__ b_xr,
    const float* __restrict__ w_hr, const float* __restrict__ b_hr,
    const float* __restrict__ w_c,  const float* __restrict__ b_c,
    const float* __restrict__ w_u,  const float* __restrict__ b_u,
    const float* __restrict__ w_o,  const float* __restrict__ b_o,
    float* __restrict__ y, float* __restrict__ h_t)
{
    __shared__ float lw[7 * 1024];     // transposed weights: lw[m*1024 + c*32 + o]
    __shared__ float lbias[4][32];     // combined biases per gate

    const int tid  = threadIdx.x;
    const int lane = tid & 63;

    // ---- stage weights transposed into LDS (coalesced global reads) ----
    {
        const float* wsrc[7] = {w_xz, w_hz, w_xr, w_hr, w_c, w_u, w_o};
#pragma unroll
        for (int m = 0; m < 7; ++m) {
            const float* wm = wsrc[m];
            for (int idx = tid; idx < 1024; idx += 256) {
                int o = idx >> 5, c = idx & 31;
                lw[m * 1024 + c * 32 + o] = wm[idx];
            }
        }
        if (tid < 32) {
            lbias[0][tid] = b_xz[tid] + b_hz[tid];
            lbias[1][tid] = b_xr[tid] + b_hr[tid];
            lbias[2][tid] = b_c[tid]  + b_u[tid];
            lbias[3][tid] = b_o[tid];
        }
    }
    __syncthreads();

    const int oo = lane & 31;          // A-frag row (output channel)
    const int cb = (lane >> 5) * 8;    // k base for this lane half
    const int rb = (lane >> 5) * 4;    // acc-layout row base offset

    // ---- build A-frags (weights) in registers: wf[m][khalf] ----
    bf16x8 wf[7][2];
#pragma unroll
    for (int m = 0; m < 7; ++m) {
        float t[16];
#pragma unroll
        for (int j = 0; j < 8; ++j) {
            t[j]     = lw[m * 1024 + (cb + j)      * 32 + oo];
            t[8 + j] = lw[m * 1024 + (cb + 16 + j) * 32 + oo];
        }
        wf[m][0] = mkfrag(pk2(t[0], t[1]),  pk2(t[2], t[3]),
                          pk2(t[4], t[5]),  pk2(t[6], t[7]));
        wf[m][1] = mkfrag(pk2(t[8], t[9]),  pk2(t[10], t[11]),
                          pk2(t[12], t[13]), pk2(t[14], t[15]));
    }

#define ACC_INIT(dst, g)                                                     \
    {                                                                        \
        _Pragma("unroll") for (int q = 0; q < 4; ++q) {                      \
            float4 bv = *reinterpret_cast<const float4*>(&lbias[g][q * 8 + rb]); \
            dst[4 * q + 0] = bv.x; dst[4 * q + 1] = bv.y;                    \
            dst[4 * q + 2] = bv.z; dst[4 * q + 3] = bv.w;                    \
        }                                                                    \
    }

    const int gw = blockIdx.x * 4 + (tid >> 6);   // global wave id
    const int NW = gridDim.x * 4;

    for (int t = gw; t < NTILE; t += NW) {
        const int p    = t * 32 + (lane & 31);
        const int base = (p >> 16) * BSTR + (p & 65535);

        // ---- load x, h in B-frag order (coalesced, 2 segs/instr) ----
        float xv[16], hv[16];
#pragma unroll
        for (int j = 0; j < 8; ++j) {
            xv[j]     = x[base + (cb + j)      * HWSZ];
            xv[8 + j] = x[base + (cb + 16 + j) * HWSZ];
            hv[j]     = h[base + (cb + j)      * HWSZ];
            hv[8 + j] = h[base + (cb + 16 + j) * HWSZ];
        }
        // ---- load h in acc layout (same cache lines -> L1 hits) ----
        float ha[16];
#pragma unroll
        for (int q = 0; q < 4; ++q)
#pragma unroll
            for (int e = 0; e < 4; ++e)
                ha[4 * q + e] = h[base + (q * 8 + rb + e) * HWSZ];

        bf16x8 xf0 = mkfrag(pk2(xv[0], xv[1]),  pk2(xv[2], xv[3]),
                            pk2(xv[4], xv[5]),  pk2(xv[6], xv[7]));
        bf16x8 xf1 = mkfrag(pk2(xv[8], xv[9]),  pk2(xv[10], xv[11]),
                            pk2(xv[12], xv[13]), pk2(xv[14], xv[15]));
        bf16x8 hf0 = mkfrag(pk2(hv[0], hv[1]),  pk2(hv[2], hv[3]),
                            pk2(hv[4], hv[5]),  pk2(hv[6], hv[7]));
        bf16x8 hf1 = mkfrag(pk2(hv[8], hv[9]),  pk2(hv[10], hv[11]),
                            pk2(hv[12], hv[13]), pk2(hv[14], hv[15]));

        // ---- z gate ----
        f32x16 az; ACC_INIT(az, 0);
        az = MFMA(wf[0][0], xf0, az);  az = MFMA(wf[0][1], xf1, az);
        az = MFMA(wf[1][0], hf0, az);  az = MFMA(wf[1][1], hf1, az);
        float zz[16];
#pragma unroll
        for (int i = 0; i < 16; ++i) zz[i] = sigm(az[i]);

        // ---- r gate, rh = sigm(ar) * h (acc layout) ----
        f32x16 ar; ACC_INIT(ar, 1);
        ar = MFMA(wf[2][0], xf0, ar);  ar = MFMA(wf[2][1], xf1, ar);
        ar = MFMA(wf[3][0], hf0, ar);  ar = MFMA(wf[3][1], hf1, ar);
        f32x16 rh;
#pragma unroll
        for (int i = 0; i < 16; ++i) rh[i] = sigm(ar[i]) * ha[i];

        bf16x8 rf0, rf1;
        acc2frag(rh, rf0, rf1);

        // ---- candidate + state update ----
        f32x16 ac; ACC_INIT(ac, 2);
        ac = MFMA(wf[4][0], xf0, ac);  ac = MFMA(wf[4][1], xf1, ac);
        ac = MFMA(wf[5][0], rf0, ac);  ac = MFMA(wf[5][1], rf1, ac);
        f32x16 ht;
#pragma unroll
        for (int i = 0; i < 16; ++i) {
            float hh = tanh_fast(ac[i]);
            ht[i] = fmaf(zz[i], hh - ha[i], ha[i]);
        }

        // ---- store h_t (acc layout, coalesced 2 segs/store) ----
#pragma unroll
        for (int q = 0; q < 4; ++q)
#pragma unroll
            for (int e = 0; e < 4; ++e)
                h_t[base + (q * 8 + rb + e) * HWSZ] = ht[4 * q + e];

        // ---- output projection y ----
        bf16x8 tf0, tf1;
        acc2frag(ht, tf0, tf1);
        f32x16 ay; ACC_INIT(ay, 3);
        ay = MFMA(wf[6][0], tf0, ay);  ay = MFMA(wf[6][1], tf1, ay);
#pragma unroll
        for (int q = 0; q < 4; ++q)
#pragma unroll
            for (int e = 0; e < 4; ++e)
                y[base + (q * 8 + rb + e) * HWSZ] = ay[4 * q + e];
    }
#undef ACC_INIT
}

extern "C" void kernel_launch(void* const* d_in, const int* in_sizes, int n_in,
                              void* d_out, int out_size, void* d_ws, size_t ws_size,
                              hipStream_t stream) {
    const float* x    = (const float*)d_in[0];
    const float* h    = (const float*)d_in[1];
    const float* w_xz = (const float*)d_in[2];
    const float* b_xz = (const float*)d_in[3];
    const float* w_hz = (const float*)d_in[4];
    const float* b_hz = (const float*)d_in[5];
    const float* w_xr = (const float*)d_in[6];
    const float* b_xr = (const float*)d_in[7];
    const float* w_hr = (const float*)d_in[8];
    const float* b_hr = (const float*)d_in[9];
    const float* w_c  = (const float*)d_in[10];
    const float* b_c  = (const float*)d_in[11];
    const float* w_u  = (const float*)d_in[12];
    const float* b_u  = (const float*)d_in[13];
    const float* w_o  = (const float*)d_in[14];
    const float* b_o  = (const float*)d_in[15];

    float* y   = (float*)d_out;
    float* h_t = (float*)d_out + (size_t)NPIX * C / C * 1 * 0 + (size_t)8 * 32 * HWSZ;

    dim3 block(256);
    dim3 grid(1024);

    gru_mfma<<<grid, block, 0, stream>>>(x, h,
        w_xz, b_xz, w_hz, b_hz, w_xr, b_xr, w_hr, b_hr,
        w_c, b_c, w_u, b_u, w_o, b_o, y, h_t);
}